// Round 1
// baseline (482.847 us; speedup 1.0000x reference)
//
#include <hip/hip_runtime.h>

// DeformConv fused pipeline, MI355X (gfx950).
// B=8, Cin=Cout=256, H=W=56, K=3x3=9, PAD=1. fp32 in/out.
// Main contraction done as split-bf16 (hi/lo) MFMA GEMM: M=256, N=25088, Kg=2304,
// error ~2^-16 relative (fp32-class), 3x bf16 MFMA per product term.

#define BATCH 8
#define CIN   256
#define COUT  256
#define HH    56
#define WW    56
#define HW    (HH*WW)            // 3136
#define NPIX  (BATCH*HW)         // 25088
#define KTAP  9
#define KG    (KTAP*CIN)         // 2304
#define NKT   (KG/64)            // 36 K-tiles of 64

typedef unsigned short ushortT;
typedef short bf16x8 __attribute__((ext_vector_type(8)));   // 8 bf16 as shorts (4 VGPRs)
typedef float f32x4 __attribute__((ext_vector_type(4)));

__device__ __forceinline__ unsigned bf16_rne(float f) {
    unsigned u = __builtin_bit_cast(unsigned, f);
    return (u + 0x7fffu + ((u >> 16) & 1u)) >> 16;
}
__device__ __forceinline__ float bf16_as_f32(unsigned h) {
    return __builtin_bit_cast(float, h << 16);
}
__device__ __forceinline__ bf16x8 lds_ld8(const ushortT* p) {
    uint4 u = *(const uint4*)p;
    return __builtin_bit_cast(bf16x8, u);
}

// ---------------------------------------------------------------------------
// K1: offset conv 3x3, Cin=256 -> 18, fp32 direct, LDS tiled.
// block = (b, 2 rows), 1024 threads: thread = (ocg 0..8)*(2 rows)*(56 cols); 2 oc each.
// x staged transposed [r4][wp][c32] so 4 channels read as one float4 (swizzled).
// ---------------------------------------------------------------------------
__global__ __launch_bounds__(1024) void k1_offconv(
    const float* __restrict__ x, const float* __restrict__ w_off,
    const float* __restrict__ b_off, float* __restrict__ off)
{
    __shared__ __align__(16) float xs[4*58*32];   // [r4][wp][c] ; c swizzled by wp
    __shared__ __align__(16) float wl[18*9*32];   // [oc][tap][c]

    const int bid = blockIdx.x;            // 0..223
    const int b   = bid / 28;
    const int h0  = (bid % 28) * 2;
    const int tid = threadIdx.x;
    const int ocg = tid / 112;
    const int rem = tid % 112;
    const int r   = rem / 56;
    const int w   = rem % 56;
    const bool active = (ocg < 9);

    float acc0 = 0.f, acc1 = 0.f;

    for (int chunk = 0; chunk < 8; ++chunk) {
        const int c0 = chunk * 32;
        __syncthreads();
        // stage x: rows h0-1..h0+2, cols -1..56, 32 channels (zero-padded)
        for (int e = tid; e < 4*58*32; e += 1024) {
            int wp = e % 58, r4 = (e / 58) % 4, c = e / (58*4);
            int row = h0 - 1 + r4, col = wp - 1;
            float v = 0.f;
            if (row >= 0 && row < HH && col >= 0 && col < WW)
                v = x[((b*CIN + c0 + c)*HH + row)*WW + col];
            xs[(r4*58 + wp)*32 + (c ^ ((wp & 7) << 2))] = v;
        }
        // stage weights [oc][tap][c]
        for (int e = tid; e < 18*9*32; e += 1024) {
            int c = e % 32, tap = (e / 32) % 9, oc = e / 288;
            wl[(oc*9 + tap)*32 + c] = w_off[(oc*CIN + c0 + c)*9 + tap];
        }
        __syncthreads();
        if (active) {
            const int oc0 = ocg * 2;
            #pragma unroll
            for (int q = 0; q < 8; ++q) {
                #pragma unroll
                for (int ky = 0; ky < 3; ++ky) {
                    #pragma unroll
                    for (int kx = 0; kx < 3; ++kx) {
                        const int wp = w + kx, r4 = r + ky, tap = ky*3 + kx;
                        const float4 xq = *(const float4*)&xs[(r4*58 + wp)*32 + ((q*4) ^ ((wp & 7) << 2))];
                        const float4 w0 = *(const float4*)&wl[((oc0    )*9 + tap)*32 + q*4];
                        const float4 w1 = *(const float4*)&wl[((oc0 + 1)*9 + tap)*32 + q*4];
                        acc0 += xq.x*w0.x + xq.y*w0.y + xq.z*w0.z + xq.w*w0.w;
                        acc1 += xq.x*w1.x + xq.y*w1.y + xq.z*w1.z + xq.w*w1.w;
                    }
                }
            }
        }
    }
    if (active) {
        const int h = h0 + r, oc0 = ocg*2;
        off[((b*18 + oc0    )*HW) + h*WW + w] = acc0 + b_off[oc0];
        off[((b*18 + oc0 + 1)*HW) + h*WW + w] = acc1 + b_off[oc0 + 1];
    }
}

// ---------------------------------------------------------------------------
// K2a: split w_conv into bf16 hi/lo, reorder kg = tap*256 + i, and pre-swizzle
// so the linear global_load_lds fill of a 256x64 K-tile lands at
// ushort idx = m*64 + (kk ^ ((m&7)<<3))  (bank-conflict-free frag reads).
// ---------------------------------------------------------------------------
__global__ void k2a_prep_w(const float* __restrict__ wconv,
                           ushortT* __restrict__ Ahi, ushortT* __restrict__ Alo)
{
    int id = blockIdx.x*256 + threadIdx.x;
    if (id >= COUT*KG) return;
    int m = id / KG, kg = id % KG;
    int k = kg >> 8, i = kg & 255;            // kg = k*256 + i
    float f = wconv[(m*CIN + i)*9 + k];
    unsigned hi = bf16_rne(f);
    unsigned lo = bf16_rne(f - bf16_as_f32(hi));
    int kt = kg >> 6, kk = kg & 63;
    int dst = kt*16384 + m*64 + (kk ^ ((m & 7) << 3));
    Ahi[dst] = (ushortT)hi;
    Alo[dst] = (ushortT)lo;
}

// ---------------------------------------------------------------------------
// K2b: bilinear sampling metadata per (b, tap, pixel): 4 absolute indices
// (clamped, channel-0 plane, batch folded in) + 4 validity-masked weights.
// ---------------------------------------------------------------------------
__global__ void k2b_meta(const float* __restrict__ off,
                         int* __restrict__ midx, float* __restrict__ mw)
{
    int id = blockIdx.x*256 + threadIdx.x;
    if (id >= KTAP*NPIX) return;
    int k = id / NPIX, np = id % NPIX;
    int b = np / HW, hw = np % HW;
    int h = hw / WW, w = hw % WW;
    float dy = off[(b*18 + 2*k    )*HW + hw];
    float dx = off[(b*18 + 2*k + 1)*HW + hw];
    float py = (float)(h - 1 + (k / 3)) + dy;
    float px = (float)(w - 1 + (k % 3)) + dx;
    py = fminf(fmaxf(py, -10000.f), 10000.f);
    px = fminf(fmaxf(px, -10000.f), 10000.f);
    float y0f = floorf(py), x0f = floorf(px);
    int y0 = (int)y0f, x0 = (int)x0f;
    float ly = py - y0f, lx = px - x0f;
    int xbase = b * (CIN*HW);
    #pragma unroll
    for (int c = 0; c < 4; ++c) {
        int yi = y0 + (c >> 1), xi = x0 + (c & 1);
        float wgt = ((c >> 1) ? ly : 1.f - ly) * ((c & 1) ? lx : 1.f - lx);
        bool valid = (yi >= 0 && yi < HH && xi >= 0 && xi < WW);
        int yc = min(max(yi, 0), HH-1), xc = min(max(xi, 0), WW-1);
        midx[(c*KTAP + k)*NPIX + np] = xbase + yc*WW + xc;
        mw  [(c*KTAP + k)*NPIX + np] = valid ? wgt : 0.f;
    }
}

// K2c: BN inference coefficients.
__global__ void k2c_bn(const float* __restrict__ g, const float* __restrict__ be,
                       const float* __restrict__ rm, const float* __restrict__ rv,
                       float* __restrict__ scale, float* __restrict__ shift)
{
    int t = threadIdx.x;
    float inv = g[t] / sqrtf(rv[t] + 1e-5f);
    scale[t] = inv;
    shift[t] = be[t] - rm[t]*inv;
}

// ---------------------------------------------------------------------------
// K3: fused deformable-im2col gather + split-bf16 MFMA GEMM + BN + ReLU.
// grid = 196 blocks (128 pixels each), 512 threads (8 waves).
// BM=256 (full Cout, gather amortized over all outputs), BN=128, BK=64.
// wave-tile 64x64 (4 M-frags x 4 N-frags of 16x16x32), 3 MFMAs per frag pair.
// ---------------------------------------------------------------------------
__global__ __launch_bounds__(512, 2) void k3_main(
    const float* __restrict__ x, const int* __restrict__ midx, const float* __restrict__ mw,
    const ushortT* __restrict__ Ahi_g, const ushortT* __restrict__ Alo_g,
    const float* __restrict__ scale_g, const float* __restrict__ shift_g,
    float* __restrict__ out)
{
    __shared__ __align__(16) ushortT Ahi_t[256*64];   // 32 KB, swizzled (pre-baked)
    __shared__ __align__(16) ushortT Alo_t[256*64];   // 32 KB
    __shared__ __align__(16) ushortT Bhi_t[128*64];   // 16 KB, swizzled
    __shared__ __align__(16) ushortT Blo_t[128*64];   // 16 KB
    __shared__ int   s_midx[512];                     // 4 corners x 128 pixels
    __shared__ float s_mw[512];
    __shared__ float s_scale[256], s_shift[256];

    const int tid = threadIdx.x;
    const int bn0 = blockIdx.x * 128;
    if (tid < 256) { s_scale[tid] = scale_g[tid]; s_shift[tid] = shift_g[tid]; }

    const int wv   = tid >> 6, lane = tid & 63;
    const int nl   = ((wv & 1) << 6) | lane;     // gather: pixel 0..127
    const int g    = wv >> 1;                    // gather: kk-group (16 ch)
    const int l16  = lane & 15, lq = lane >> 4;
    const int mbase = (wv >> 1) * 64;            // mfma: wave M-origin
    const int nbase = (wv & 1) * 64;             // mfma: wave N-origin

    f32x4 acc[4][4] = {};

    for (int kt = 0; kt < NKT; ++kt) {
        const int tap = kt >> 2, ic = kt & 3;
        __syncthreads();                          // prev MFMA done -> safe to overwrite
        if (ic == 0) {                            // stage bilinear meta for this tap
            const int c = tid >> 7, j = tid & 127;
            s_midx[tid] = midx[(c*KTAP + tap)*NPIX + bn0 + j];
            s_mw[tid]   = mw  [(c*KTAP + tap)*NPIX + bn0 + j];
            __syncthreads();
        }
        // --- async A-tile stage (linear fill of pre-swizzled layout) ---
        {
            const char* gh = (const char*)Ahi_g + (size_t)kt*32768;
            const char* gl = (const char*)Alo_g + (size_t)kt*32768;
            char* lh = (char*)Ahi_t + wv*1024;    // wave-uniform LDS base
            char* ll = (char*)Alo_t + wv*1024;
            #pragma unroll
            for (int it = 0; it < 4; ++it) {
                __builtin_amdgcn_global_load_lds(
                    (const __attribute__((address_space(1))) unsigned*)(gh + it*8192 + tid*16),
                    (__attribute__((address_space(3))) unsigned*)(lh + it*8192), 16, 0, 0);
                __builtin_amdgcn_global_load_lds(
                    (const __attribute__((address_space(1))) unsigned*)(gl + it*8192 + tid*16),
                    (__attribute__((address_space(3))) unsigned*)(ll + it*8192), 16, 0, 0);
            }
        }
        // --- gather B-tile: 16 channels per thread, bilinear blend, hi/lo split ---
        {
            const int i0 = ic*64 + g*16;
            const float* p0; const float* p1; const float* p2; const float* p3;
            float fw0, fw1, fw2, fw3;
            p0 = x + (size_t)s_midx[0*128 + nl] + (size_t)i0*HW; fw0 = s_mw[0*128 + nl];
            p1 = x + (size_t)s_midx[1*128 + nl] + (size_t)i0*HW; fw1 = s_mw[1*128 + nl];
            p2 = x + (size_t)s_midx[2*128 + nl] + (size_t)i0*HW; fw2 = s_mw[2*128 + nl];
            p3 = x + (size_t)s_midx[3*128 + nl] + (size_t)i0*HW; fw3 = s_mw[3*128 + nl];
            #pragma unroll
            for (int half = 0; half < 2; ++half) {
                unsigned ph[4], pl[4];
                #pragma unroll
                for (int q = 0; q < 4; ++q) {
                    const int j0 = half*8 + q*2;
                    float v0 = fw0*p0[(size_t)j0*HW] + fw1*p1[(size_t)j0*HW]
                             + fw2*p2[(size_t)j0*HW] + fw3*p3[(size_t)j0*HW];
                    float v1 = fw0*p0[(size_t)(j0+1)*HW] + fw1*p1[(size_t)(j0+1)*HW]
                             + fw2*p2[(size_t)(j0+1)*HW] + fw3*p3[(size_t)(j0+1)*HW];
                    unsigned h0 = bf16_rne(v0), h1 = bf16_rne(v1);
                    unsigned l0 = bf16_rne(v0 - bf16_as_f32(h0));
                    unsigned l1 = bf16_rne(v1 - bf16_as_f32(h1));
                    ph[q] = h0 | (h1 << 16);
                    pl[q] = l0 | (l1 << 16);
                }
                const int idx = nl*64 + ((g*16 + half*8) ^ ((nl & 7) << 3));
                *(uint4*)&Bhi_t[idx] = make_uint4(ph[0], ph[1], ph[2], ph[3]);
                *(uint4*)&Blo_t[idx] = make_uint4(pl[0], pl[1], pl[2], pl[3]);
            }
        }
        __syncthreads();   // drains vmcnt (A async) + lgkm (B writes)
        // --- MFMA phase: 2 K-steps of 32, 4x4 frags, 3 split products ---
        #pragma unroll
        for (int ks = 0; ks < 2; ++ks) {
            const int kk0 = ks*32 + lq*8;
            bf16x8 ah[4], al[4], bh[4], bl[4];
            #pragma unroll
            for (int mf = 0; mf < 4; ++mf) {
                const int m = mbase + mf*16 + l16;
                const int idx = m*64 + (kk0 ^ ((m & 7) << 3));
                ah[mf] = lds_ld8(&Ahi_t[idx]);
                al[mf] = lds_ld8(&Alo_t[idx]);
            }
            #pragma unroll
            for (int nf = 0; nf < 4; ++nf) {
                const int n = nbase + nf*16 + l16;
                const int idx = n*64 + (kk0 ^ ((n & 7) << 3));
                bh[nf] = lds_ld8(&Bhi_t[idx]);
                bl[nf] = lds_ld8(&Blo_t[idx]);
            }
            #pragma unroll
            for (int mf = 0; mf < 4; ++mf) {
                #pragma unroll
                for (int nf = 0; nf < 4; ++nf) {
                    acc[mf][nf] = __builtin_amdgcn_mfma_f32_16x16x32_bf16(ah[mf], bh[nf], acc[mf][nf], 0, 0, 0);
                    acc[mf][nf] = __builtin_amdgcn_mfma_f32_16x16x32_bf16(ah[mf], bl[nf], acc[mf][nf], 0, 0, 0);
                    acc[mf][nf] = __builtin_amdgcn_mfma_f32_16x16x32_bf16(al[mf], bh[nf], acc[mf][nf], 0, 0, 0);
                }
            }
        }
    }
    // --- epilogue: BN + ReLU + store (D frag: row = lq*4+r, col = l16) ---
    #pragma unroll
    for (int mf = 0; mf < 4; ++mf) {
        #pragma unroll
        for (int nf = 0; nf < 4; ++nf) {
            const int n = bn0 + nbase + nf*16 + l16;
            const int b = n / HW, hw = n % HW;
            const int m0 = mbase + mf*16 + lq*4;
            float* op = out + ((size_t)b*COUT + m0)*HW + hw;
            const f32x4 v = acc[mf][nf];
            #pragma unroll
            for (int r = 0; r < 4; ++r) {
                float val = fmaxf(v[r]*s_scale[m0 + r] + s_shift[m0 + r], 0.f);
                op[(size_t)r*HW] = val;
            }
        }
    }
}

// ---------------------------------------------------------------------------
extern "C" void kernel_launch(void* const* d_in, const int* in_sizes, int n_in,
                              void* d_out, int out_size, void* d_ws, size_t ws_size,
                              hipStream_t stream)
{
    const float* x      = (const float*)d_in[0];
    const float* w_off  = (const float*)d_in[1];
    const float* b_off  = (const float*)d_in[2];
    const float* w_conv = (const float*)d_in[3];
    const float* gamma  = (const float*)d_in[4];
    const float* beta   = (const float*)d_in[5];
    const float* rmean  = (const float*)d_in[6];
    const float* rvar   = (const float*)d_in[7];
    float* out = (float*)d_out;
    char* ws = (char*)d_ws;

    // workspace layout (bytes), total ~10.9 MB
    float*   off   = (float*)(ws + 0);          //  451584 f32
    int*     midx  = (int*)  (ws + 1806336);    //  903168 i32
    float*   mwt   = (float*)(ws + 5419008);    //  903168 f32
    ushortT* Ahi   = (ushortT*)(ws + 9031680);  //  589824 u16
    ushortT* Alo   = (ushortT*)(ws + 10211328); //  589824 u16
    float*   scale = (float*)(ws + 11390976);   //  256 f32
    float*   shift = (float*)(ws + 11392000);   //  256 f32

    hipLaunchKernelGGL(k1_offconv, dim3(BATCH*28), dim3(1024), 0, stream, x, w_off, b_off, off);
    hipLaunchKernelGGL(k2a_prep_w, dim3((COUT*KG + 255)/256), dim3(256), 0, stream, w_conv, Ahi, Alo);
    hipLaunchKernelGGL(k2c_bn,     dim3(1), dim3(256), 0, stream, gamma, beta, rmean, rvar, scale, shift);
    hipLaunchKernelGGL(k2b_meta,   dim3((KTAP*NPIX + 255)/256), dim3(256), 0, stream, off, midx, mwt);
    hipLaunchKernelGGL(k3_main,    dim3(NPIX/128), dim3(512), 0, stream,
                       x, midx, mwt, Ahi, Alo, scale, shift, out);
}

// Round 2
// 241.843 us; speedup vs baseline: 1.9965x; 1.9965x over previous
//
#include <hip/hip_runtime.h>

// DeformConv fused pipeline v2, MI355X (gfx950).
// x -> NHWC transpose -> offset conv (fp16 MFMA thin GEMM) -> bilinear meta ->
// fused gather + fp16 (A single / B hi+lo split) MFMA GEMM + BN + ReLU.

#define BATCH 8
#define CIN   256
#define COUT  256
#define HH    56
#define WW    56
#define HW    (HH*WW)            // 3136
#define NPIX  (BATCH*HW)         // 25088
#define KTAP  9
#define KG    (KTAP*CIN)         // 2304
#define NKT   (KG/64)            // 36 K-tiles of 64

typedef unsigned short ushortT;
typedef _Float16 f16x8 __attribute__((ext_vector_type(8)));
typedef float f32x4 __attribute__((ext_vector_type(4)));

__device__ __forceinline__ f16x8 lds_ldh8(const ushortT* p) {
    uint4 u = *(const uint4*)p;
    return __builtin_bit_cast(f16x8, u);
}
__device__ __forceinline__ unsigned packh2(float v0, float v1) {
    _Float16 h0 = (_Float16)v0, h1 = (_Float16)v1;
    return (unsigned)__builtin_bit_cast(unsigned short, h0)
         | ((unsigned)__builtin_bit_cast(unsigned short, h1) << 16);
}

// ---------------------------------------------------------------------------
// K0: transpose x NCHW -> xt NHWC (fp32). Tiles 64hw x 64c via LDS.
// ---------------------------------------------------------------------------
__global__ __launch_bounds__(256) void k0_transpose(
    const float* __restrict__ x, float* __restrict__ xt)
{
    __shared__ float t[64][65];
    const int bid = blockIdx.x;                 // 8 * 49 * 4 = 1568
    const int b   = bid / 196;
    const int r   = bid % 196;
    const int hw0 = (r >> 2) * 64;
    const int c0  = (r & 3) * 64;
    const int tid = threadIdx.x;

    {   // load: thread = (c_l, hw-chunk of 16)
        const int c_l = tid >> 2, ch = (tid & 3) * 16;
        const float* src = x + ((size_t)(b*CIN + c0 + c_l))*HW + hw0 + ch;
        float4 v0 = *(const float4*)(src + 0);
        float4 v1 = *(const float4*)(src + 4);
        float4 v2 = *(const float4*)(src + 8);
        float4 v3 = *(const float4*)(src + 12);
        *(float4*)&t[c_l][ch + 0]  = v0;
        *(float4*)&t[c_l][ch + 4]  = v1;
        *(float4*)&t[c_l][ch + 8]  = v2;
        *(float4*)&t[c_l][ch + 12] = v3;
    }
    __syncthreads();
    {   // store: thread = (hw_l, c-chunk of 16)
        const int hw_l = tid >> 2, cc = (tid & 3) * 16;
        float* dst = xt + ((size_t)(b*HW + hw0 + hw_l))*CIN + c0 + cc;
        #pragma unroll
        for (int q = 0; q < 4; ++q) {
            float4 o;
            o.x = t[cc + q*4 + 0][hw_l];
            o.y = t[cc + q*4 + 1][hw_l];
            o.z = t[cc + q*4 + 2][hw_l];
            o.w = t[cc + q*4 + 3][hw_l];
            *(float4*)(dst + q*4) = o;
        }
    }
}

// ---------------------------------------------------------------------------
// K2a: prep weights as fp16, tap-major kg = k*256+i, swizzle baked in.
//  Ah  : w_conv, 256x2304, tile stride 16384
//  A0h : w_off padded to 32 rows, tile stride 2048
// ---------------------------------------------------------------------------
__global__ void k2a_prep_w(const float* __restrict__ wconv, const float* __restrict__ woff,
                           ushortT* __restrict__ Ah, ushortT* __restrict__ A0h)
{
    int id = blockIdx.x*256 + threadIdx.x;
    if (id < COUT*KG) {
        int m = id / KG, kg = id % KG;
        int k = kg >> 8, i = kg & 255;
        float f = wconv[(m*CIN + i)*9 + k];
        int kt = kg >> 6, kk = kg & 63;
        _Float16 h = (_Float16)f;
        Ah[kt*16384 + m*64 + (kk ^ ((m & 7) << 3))] = __builtin_bit_cast(unsigned short, h);
    } else if (id < COUT*KG + 32*KG) {
        int id2 = id - COUT*KG;
        int m = id2 / KG, kg = id2 % KG;
        int k = kg >> 8, i = kg & 255;
        float f = (m < 18) ? woff[(m*CIN + i)*9 + k] : 0.f;
        int kt = kg >> 6, kk = kg & 63;
        _Float16 h = (_Float16)f;
        A0h[kt*2048 + m*64 + (kk ^ ((m & 7) << 3))] = __builtin_bit_cast(unsigned short, h);
    }
}

// ---------------------------------------------------------------------------
// K1: offset conv as thin MFMA GEMM. M=32(18), N=25088, K=2304, pure fp16.
// grid 392 x 256 thr (4 waves), BN=64, BK=64. B = straight im2col from xt.
// ---------------------------------------------------------------------------
__global__ __launch_bounds__(256) void k1_offmfma(
    const float* __restrict__ xt, const ushortT* __restrict__ A0h_g,
    const float* __restrict__ b_off, float* __restrict__ off)
{
    __shared__ __align__(16) ushortT A0[32*64];   // 4 KB
    __shared__ __align__(16) ushortT Bh[64*64];   // 8 KB

    const int tid = threadIdx.x;
    const int bn0 = blockIdx.x * 64;
    const int wv = tid >> 6, lane = tid & 63;
    const int l16 = lane & 15, lq = lane >> 4;
    const int px_l = tid >> 2, g2 = tid & 3;

    const int np = bn0 + px_l;
    const int hw = np % HW;
    const int h = hw / WW, w = hw % WW;

    f32x4 acc[2] = {};

    for (int kt = 0; kt < NKT; ++kt) {
        const int tap = kt >> 2, ic = kt & 3;
        const int ky = tap / 3 - 1, kx = tap % 3 - 1;
        __syncthreads();
        // stage A0 (4096 B, one shot)
        __builtin_amdgcn_global_load_lds(
            (const __attribute__((address_space(1))) unsigned*)((const char*)A0h_g + kt*4096 + tid*16),
            (__attribute__((address_space(3))) unsigned*)((char*)A0 + wv*1024), 16, 0, 0);
        // B: straight im2col, 16 ch per thread
        {
            const int hs = h + ky, ws = w + kx;
            const bool valid = (hs >= 0 && hs < HH && ws >= 0 && ws < WW);
            const float* p = xt + ((size_t)(np + ky*WW + kx))*CIN + ic*64 + g2*16;
            float4 v0, v1, v2, v3;
            if (valid) {
                v0 = *(const float4*)(p + 0);  v1 = *(const float4*)(p + 4);
                v2 = *(const float4*)(p + 8);  v3 = *(const float4*)(p + 12);
            } else {
                v0 = v1 = v2 = v3 = make_float4(0.f, 0.f, 0.f, 0.f);
            }
            uint4 h0, h1;
            h0.x = packh2(v0.x, v0.y); h0.y = packh2(v0.z, v0.w);
            h0.z = packh2(v1.x, v1.y); h0.w = packh2(v1.z, v1.w);
            h1.x = packh2(v2.x, v2.y); h1.y = packh2(v2.z, v2.w);
            h1.z = packh2(v3.x, v3.y); h1.w = packh2(v3.z, v3.w);
            const int base = g2 * 16;
            *(uint4*)&Bh[px_l*64 + ((base + 0) ^ ((px_l & 7) << 3))] = h0;
            *(uint4*)&Bh[px_l*64 + ((base + 8) ^ ((px_l & 7) << 3))] = h1;
        }
        __syncthreads();
        #pragma unroll
        for (int ks = 0; ks < 2; ++ks) {
            const int kk0 = ks*32 + lq*8;
            f16x8 a0, a1, b;
            {
                const int m0 = l16, m1 = 16 + l16;
                a0 = lds_ldh8(&A0[m0*64 + (kk0 ^ ((m0 & 7) << 3))]);
                a1 = lds_ldh8(&A0[m1*64 + (kk0 ^ ((m1 & 7) << 3))]);
            }
            {
                const int n = wv*16 + l16;
                b = lds_ldh8(&Bh[n*64 + (kk0 ^ ((n & 7) << 3))]);
            }
            acc[0] = __builtin_amdgcn_mfma_f32_16x16x32_f16(a0, b, acc[0], 0, 0, 0);
            acc[1] = __builtin_amdgcn_mfma_f32_16x16x32_f16(a1, b, acc[1], 0, 0, 0);
        }
    }
    // epilogue
    const int n = bn0 + wv*16 + l16;
    const int b2 = n / HW, hw2 = n % HW;
    #pragma unroll
    for (int mf = 0; mf < 2; ++mf) {
        #pragma unroll
        for (int r = 0; r < 4; ++r) {
            const int m = mf*16 + lq*4 + r;
            if (m < 18)
                off[((size_t)b2*18 + m)*HW + hw2] = acc[mf][r] + b_off[m];
        }
    }
}

// ---------------------------------------------------------------------------
// K2b: bilinear metadata. midx = element offset into xt (row * 256).
// ---------------------------------------------------------------------------
__global__ void k2b_meta(const float* __restrict__ off,
                         int* __restrict__ midx, float* __restrict__ mw)
{
    int id = blockIdx.x*256 + threadIdx.x;
    if (id >= KTAP*NPIX) return;
    int k = id / NPIX, np = id % NPIX;
    int b = np / HW, hw = np % HW;
    int h = hw / WW, w = hw % WW;
    float dy = off[((size_t)b*18 + 2*k    )*HW + hw];
    float dx = off[((size_t)b*18 + 2*k + 1)*HW + hw];
    float py = (float)(h - 1 + (k / 3)) + dy;
    float px = (float)(w - 1 + (k % 3)) + dx;
    py = fminf(fmaxf(py, -10000.f), 10000.f);
    px = fminf(fmaxf(px, -10000.f), 10000.f);
    float y0f = floorf(py), x0f = floorf(px);
    int y0 = (int)y0f, x0 = (int)x0f;
    float ly = py - y0f, lx = px - x0f;
    #pragma unroll
    for (int c = 0; c < 4; ++c) {
        int yi = y0 + (c >> 1), xi = x0 + (c & 1);
        float wgt = ((c >> 1) ? ly : 1.f - ly) * ((c & 1) ? lx : 1.f - lx);
        bool valid = (yi >= 0 && yi < HH && xi >= 0 && xi < WW);
        int yc = min(max(yi, 0), HH-1), xc = min(max(xi, 0), WW-1);
        midx[(c*KTAP + k)*NPIX + np] = (b*HW + yc*WW + xc) * CIN;
        mw  [(c*KTAP + k)*NPIX + np] = valid ? wgt : 0.f;
    }
}

// K2c: BN inference coefficients.
__global__ void k2c_bn(const float* __restrict__ g, const float* __restrict__ be,
                       const float* __restrict__ rm, const float* __restrict__ rv,
                       float* __restrict__ scale, float* __restrict__ shift)
{
    int t = threadIdx.x;
    float inv = g[t] / sqrtf(rv[t] + 1e-5f);
    scale[t] = inv;
    shift[t] = be[t] - rm[t]*inv;
}

// ---------------------------------------------------------------------------
// K3: fused gather + fp16 MFMA GEMM (A single, B hi/lo split) + BN + ReLU.
// grid 392 (64 px each), 512 thr (8 waves). BM=256, BN=64, BK=64.
// wave-tile 64x32 (4 M-frags x 2 N-frags), 2 MFMAs per frag pair.
// ---------------------------------------------------------------------------
__global__ __launch_bounds__(512) void k3_main(
    const float* __restrict__ xt, const int* __restrict__ midx, const float* __restrict__ mw,
    const ushortT* __restrict__ Ah_g, const float* __restrict__ scale_g,
    const float* __restrict__ shift_g, float* __restrict__ out)
{
    __shared__ __align__(16) ushortT Ah_t[256*64];   // 32 KB swizzled (pre-baked)
    __shared__ __align__(16) ushortT Bh_t[64*64];    // 8 KB swizzled
    __shared__ __align__(16) ushortT Bl_t[64*64];    // 8 KB
    __shared__ int   s_midx[256];                    // 4 corners x 64 px
    __shared__ float s_mw[256];
    __shared__ float s_scale[256], s_shift[256];

    const int tid = threadIdx.x;
    const int bn0 = blockIdx.x * 64;
    if (tid < 256) { s_scale[tid] = scale_g[tid]; s_shift[tid] = shift_g[tid]; }

    const int wv = tid >> 6, lane = tid & 63;
    const int l16 = lane & 15, lq = lane >> 4;
    const int mbase = (wv >> 1) * 64;            // 4 M-wave rows
    const int nbase = (wv & 1) * 32;             // 2 N-wave cols
    const int px_l = tid >> 3, g = tid & 7;      // gather: 8 thr/px, 8 ch each

    f32x4 acc[4][2] = {};

    for (int kt = 0; kt < NKT; ++kt) {
        const int tap = kt >> 2, ic = kt & 3;
        __syncthreads();
        if (ic == 0) {
            if (tid < 256) {
                const int c = tid >> 6, px = tid & 63;
                s_midx[tid] = midx[(c*KTAP + tap)*NPIX + bn0 + px];
                s_mw[tid]   = mw  [(c*KTAP + tap)*NPIX + bn0 + px];
            }
            __syncthreads();
        }
        // --- async A stage: 32 KB, 4 iters of 512x16B ---
        {
            const char* gh = (const char*)Ah_g + (size_t)kt*32768;
            #pragma unroll
            for (int it = 0; it < 4; ++it) {
                __builtin_amdgcn_global_load_lds(
                    (const __attribute__((address_space(1))) unsigned*)(gh + it*8192 + tid*16),
                    (__attribute__((address_space(3))) unsigned*)((char*)Ah_t + it*8192 + wv*1024), 16, 0, 0);
            }
        }
        // --- gather B: 8 contiguous channels x 4 corners, blend, fp16 split ---
        {
            const float* base = xt + (size_t)(ic*64 + g*8);
            const float* p0 = base + s_midx[0*64 + px_l]; const float fw0 = s_mw[0*64 + px_l];
            const float* p1 = base + s_midx[1*64 + px_l]; const float fw1 = s_mw[1*64 + px_l];
            const float* p2 = base + s_midx[2*64 + px_l]; const float fw2 = s_mw[2*64 + px_l];
            const float* p3 = base + s_midx[3*64 + px_l]; const float fw3 = s_mw[3*64 + px_l];
            float4 a0 = *(const float4*)(p0 + 0), a1 = *(const float4*)(p0 + 4);
            float4 b0 = *(const float4*)(p1 + 0), b1 = *(const float4*)(p1 + 4);
            float4 c0 = *(const float4*)(p2 + 0), c1 = *(const float4*)(p2 + 4);
            float4 d0 = *(const float4*)(p3 + 0), d1 = *(const float4*)(p3 + 4);
            float v[8];
            v[0] = fw0*a0.x + fw1*b0.x + fw2*c0.x + fw3*d0.x;
            v[1] = fw0*a0.y + fw1*b0.y + fw2*c0.y + fw3*d0.y;
            v[2] = fw0*a0.z + fw1*b0.z + fw2*c0.z + fw3*d0.z;
            v[3] = fw0*a0.w + fw1*b0.w + fw2*c0.w + fw3*d0.w;
            v[4] = fw0*a1.x + fw1*b1.x + fw2*c1.x + fw3*d1.x;
            v[5] = fw0*a1.y + fw1*b1.y + fw2*c1.y + fw3*d1.y;
            v[6] = fw0*a1.z + fw1*b1.z + fw2*c1.z + fw3*d1.z;
            v[7] = fw0*a1.w + fw1*b1.w + fw2*c1.w + fw3*d1.w;
            uint4 hi, lo;
            float r[8];
            #pragma unroll
            for (int j = 0; j < 8; ++j) {
                _Float16 hh = (_Float16)v[j];
                r[j] = v[j] - (float)hh;
            }
            hi.x = packh2(v[0], v[1]); hi.y = packh2(v[2], v[3]);
            hi.z = packh2(v[4], v[5]); hi.w = packh2(v[6], v[7]);
            lo.x = packh2(r[0], r[1]); lo.y = packh2(r[2], r[3]);
            lo.z = packh2(r[4], r[5]); lo.w = packh2(r[6], r[7]);
            const int idx = px_l*64 + ((g*8) ^ ((px_l & 7) << 3));
            *(uint4*)&Bh_t[idx] = hi;
            *(uint4*)&Bl_t[idx] = lo;
        }
        __syncthreads();   // drains vmcnt (A async) + lgkm (B writes)
        // --- MFMA: 2 K-steps, 4x2 frags, 2 terms ---
        #pragma unroll
        for (int ks = 0; ks < 2; ++ks) {
            const int kk0 = ks*32 + lq*8;
            f16x8 a[4], bh[2], bl[2];
            #pragma unroll
            for (int mf = 0; mf < 4; ++mf) {
                const int m = mbase + mf*16 + l16;
                a[mf] = lds_ldh8(&Ah_t[m*64 + (kk0 ^ ((m & 7) << 3))]);
            }
            #pragma unroll
            for (int nf = 0; nf < 2; ++nf) {
                const int n = nbase + nf*16 + l16;
                const int idx = n*64 + (kk0 ^ ((n & 7) << 3));
                bh[nf] = lds_ldh8(&Bh_t[idx]);
                bl[nf] = lds_ldh8(&Bl_t[idx]);
            }
            #pragma unroll
            for (int mf = 0; mf < 4; ++mf) {
                #pragma unroll
                for (int nf = 0; nf < 2; ++nf) {
                    acc[mf][nf] = __builtin_amdgcn_mfma_f32_16x16x32_f16(a[mf], bh[nf], acc[mf][nf], 0, 0, 0);
                    acc[mf][nf] = __builtin_amdgcn_mfma_f32_16x16x32_f16(a[mf], bl[nf], acc[mf][nf], 0, 0, 0);
                }
            }
        }
    }
    // --- epilogue: BN + ReLU + store ---
    #pragma unroll
    for (int mf = 0; mf < 4; ++mf) {
        #pragma unroll
        for (int nf = 0; nf < 2; ++nf) {
            const int n = bn0 + nbase + nf*16 + l16;
            const int b = n / HW, hw = n % HW;
            const int m0 = mbase + mf*16 + lq*4;
            float* op = out + ((size_t)b*COUT + m0)*HW + hw;
            const f32x4 v = acc[mf][nf];
            #pragma unroll
            for (int r = 0; r < 4; ++r) {
                float val = fmaxf(v[r]*s_scale[m0 + r] + s_shift[m0 + r], 0.f);
                op[(size_t)r*HW] = val;
            }
        }
    }
}

// ---------------------------------------------------------------------------
extern "C" void kernel_launch(void* const* d_in, const int* in_sizes, int n_in,
                              void* d_out, int out_size, void* d_ws, size_t ws_size,
                              hipStream_t stream)
{
    const float* x      = (const float*)d_in[0];
    const float* w_off  = (const float*)d_in[1];
    const float* b_off  = (const float*)d_in[2];
    const float* w_conv = (const float*)d_in[3];
    const float* gamma  = (const float*)d_in[4];
    const float* beta   = (const float*)d_in[5];
    const float* rmean  = (const float*)d_in[6];
    const float* rvar   = (const float*)d_in[7];
    float* out = (float*)d_out;
    char* ws = (char*)d_ws;

    // workspace layout (bytes), total ~36 MB
    float*   xt    = (float*)(ws + 0);           // 6422528 f32 = 25690112 B
    float*   off   = (float*)(ws + 25690112);    //  451584 f32 =  1806336 B
    int*     midx  = (int*)  (ws + 27496448);    //  903168 i32 =  3612672 B
    float*   mwt   = (float*)(ws + 31109120);    //  903168 f32 =  3612672 B
    ushortT* Ah    = (ushortT*)(ws + 34721792);  //  589824 u16 =  1179648 B
    ushortT* A0h   = (ushortT*)(ws + 35901440);  //   73728 u16 =   147456 B
    float*   scale = (float*)(ws + 36048896);    //  256 f32
    float*   shift = (float*)(ws + 36049920);    //  256 f32

    hipLaunchKernelGGL(k0_transpose, dim3(1568), dim3(256), 0, stream, x, xt);
    hipLaunchKernelGGL(k2a_prep_w, dim3((COUT*KG + 32*KG + 255)/256), dim3(256), 0, stream,
                       w_conv, w_off, Ah, A0h);
    hipLaunchKernelGGL(k2c_bn, dim3(1), dim3(256), 0, stream, gamma, beta, rmean, rvar, scale, shift);
    hipLaunchKernelGGL(k1_offmfma, dim3(NPIX/64), dim3(256), 0, stream, xt, A0h, b_off, off);
    hipLaunchKernelGGL(k2b_meta, dim3((KTAP*NPIX + 255)/256), dim3(256), 0, stream, off, midx, mwt);
    hipLaunchKernelGGL(k3_main, dim3(NPIX/64), dim3(512), 0, stream,
                       xt, midx, mwt, Ah, scale, shift, out);
}

// Round 4
// 216.583 us; speedup vs baseline: 2.2294x; 1.1166x over previous
//
#include <hip/hip_runtime.h>

// DeformConv fused pipeline v3.1, MI355X (gfx950).
// v3: k3 software-pipelined (1-ahead reg gather, counted vmcnt, raw barriers),
//     XCD-chunked block maps (image-per-XCD), k1 K-split x4 with atomic off,
//     compact bilinear meta.
// v3.1: + s_setprio around MFMA cluster (T5), sched_barrier hardening.

#define BATCH 8
#define CIN   256
#define COUT  256
#define HH    56
#define WW    56
#define HW    3136
#define NPIX  25088
#define KTAP  9
#define KG    2304
#define NKT   36

typedef unsigned short ushortT;
typedef _Float16 f16x8 __attribute__((ext_vector_type(8)));
typedef float f32x4 __attribute__((ext_vector_type(4)));

__device__ __forceinline__ f16x8 lds_ldh8(const ushortT* p) {
    uint4 u = *(const uint4*)p;
    return __builtin_bit_cast(f16x8, u);
}
__device__ __forceinline__ unsigned packh2(float v0, float v1) {
    _Float16 h0 = (_Float16)v0, h1 = (_Float16)v1;
    return (unsigned)__builtin_bit_cast(unsigned short, h0)
         | ((unsigned)__builtin_bit_cast(unsigned short, h1) << 16);
}

// ---------------------------------------------------------------------------
// K0: transpose x NCHW -> xt NHWC (fp32), XCD-chunked (image per XCD).
// ---------------------------------------------------------------------------
__global__ __launch_bounds__(256) void k0_transpose(
    const float* __restrict__ x, float* __restrict__ xt)
{
    __shared__ float t[64][65];
    const int bid = (blockIdx.x & 7) * 196 + (blockIdx.x >> 3);   // 1568 = 8*196
    const int b   = bid / 196;
    const int r   = bid % 196;
    const int hw0 = (r >> 2) * 64;
    const int c0  = (r & 3) * 64;
    const int tid = threadIdx.x;

    {
        const int c_l = tid >> 2, ch = (tid & 3) * 16;
        const float* src = x + ((size_t)(b*CIN + c0 + c_l))*HW + hw0 + ch;
        float4 v0 = *(const float4*)(src + 0);
        float4 v1 = *(const float4*)(src + 4);
        float4 v2 = *(const float4*)(src + 8);
        float4 v3 = *(const float4*)(src + 12);
        *(float4*)&t[c_l][ch + 0]  = v0;
        *(float4*)&t[c_l][ch + 4]  = v1;
        *(float4*)&t[c_l][ch + 8]  = v2;
        *(float4*)&t[c_l][ch + 12] = v3;
    }
    __syncthreads();
    {
        const int hw_l = tid >> 2, cc = (tid & 3) * 16;
        float* dst = xt + ((size_t)(b*HW + hw0 + hw_l))*CIN + c0 + cc;
        #pragma unroll
        for (int q = 0; q < 4; ++q) {
            float4 o;
            o.x = t[cc + q*4 + 0][hw_l];
            o.y = t[cc + q*4 + 1][hw_l];
            o.z = t[cc + q*4 + 2][hw_l];
            o.w = t[cc + q*4 + 3][hw_l];
            *(float4*)(dst + q*4) = o;
        }
    }
}

// ---------------------------------------------------------------------------
// K2a: weight prep (fp16, tap-major, swizzle baked) + BN coefficients.
// ---------------------------------------------------------------------------
__global__ void k2a_prep(const float* __restrict__ wconv, const float* __restrict__ woff,
                         const float* __restrict__ g, const float* __restrict__ be,
                         const float* __restrict__ rm, const float* __restrict__ rv,
                         ushortT* __restrict__ Ah, ushortT* __restrict__ A0h,
                         float* __restrict__ scale, float* __restrict__ shift)
{
    int id = blockIdx.x*256 + threadIdx.x;
    if (id < COUT*KG) {
        int m = id / KG, kg = id % KG;
        int k = kg >> 8, i = kg & 255;
        float f = wconv[(m*CIN + i)*9 + k];
        int kt = kg >> 6, kk = kg & 63;
        _Float16 h = (_Float16)f;
        Ah[kt*16384 + m*64 + (kk ^ ((m & 7) << 3))] = __builtin_bit_cast(unsigned short, h);
    } else if (id < COUT*KG + 32*KG) {
        int id2 = id - COUT*KG;
        int m = id2 / KG, kg = id2 % KG;
        int k = kg >> 8, i = kg & 255;
        float f = (m < 18) ? woff[(m*CIN + i)*9 + k] : 0.f;
        int kt = kg >> 6, kk = kg & 63;
        _Float16 h = (_Float16)f;
        A0h[kt*2048 + m*64 + (kk ^ ((m & 7) << 3))] = __builtin_bit_cast(unsigned short, h);
    } else if (id < COUT*KG + 32*KG + 256) {
        int t = id - (COUT*KG + 32*KG);
        float inv = g[t] / sqrtf(rv[t] + 1e-5f);
        scale[t] = inv;
        shift[t] = be[t] - rm[t]*inv;
    }
}

// ---------------------------------------------------------------------------
// K1: offset conv thin MFMA GEMM, K-split x4, atomicAdd partials.
// grid 1568 = 8 xcd * (49 tiles * 4 ksplit); 256 thr (4 waves), BN=64, BK=64.
// ---------------------------------------------------------------------------
__global__ __launch_bounds__(256) void k1_offmfma(
    const float* __restrict__ xt, const ushortT* __restrict__ A0h_g,
    float* __restrict__ off)
{
    __shared__ __align__(16) ushortT A0[32*64];   // 4 KB
    __shared__ __align__(16) ushortT Bh[64*64];   // 8 KB

    const int tid = threadIdx.x;
    const int x8 = blockIdx.x & 7;        // xcd == image
    const int j  = blockIdx.x >> 3;       // [0,196)
    const int tile = x8*49 + (j % 49);    // global pixel-tile
    const int ks = j / 49;                // K-split slice [0,4)
    const int bn0 = tile * 64;

    const int wv = tid >> 6, lane = tid & 63;
    const int l16 = lane & 15, lq = lane >> 4;
    const int px_l = tid >> 2, g2 = tid & 3;

    const int np = bn0 + px_l;
    const int hw = np - x8*HW;
    const int h = hw / WW, w = hw % WW;

    f32x4 acc[2] = {};

    for (int t = 0; t < 9; ++t) {
        const int ktg = ks*9 + t;
        const int tap = ktg >> 2, ic = ktg & 3;
        const int ky = tap / 3 - 1, kx = tap % 3 - 1;
        __syncthreads();
        __builtin_amdgcn_global_load_lds(
            (const __attribute__((address_space(1))) unsigned*)((const char*)A0h_g + ktg*4096 + tid*16),
            (__attribute__((address_space(3))) unsigned*)((char*)A0 + wv*1024), 16, 0, 0);
        {
            const int hs = h + ky, ws2 = w + kx;
            const bool valid = (hs >= 0 && hs < HH && ws2 >= 0 && ws2 < WW);
            const float* p = xt + ((size_t)(np + ky*WW + kx))*CIN + ic*64 + g2*16;
            float4 v0, v1, v2, v3;
            if (valid) {
                v0 = *(const float4*)(p + 0);  v1 = *(const float4*)(p + 4);
                v2 = *(const float4*)(p + 8);  v3 = *(const float4*)(p + 12);
            } else {
                v0 = v1 = v2 = v3 = make_float4(0.f, 0.f, 0.f, 0.f);
            }
            uint4 h0, h1;
            h0.x = packh2(v0.x, v0.y); h0.y = packh2(v0.z, v0.w);
            h0.z = packh2(v1.x, v1.y); h0.w = packh2(v1.z, v1.w);
            h1.x = packh2(v2.x, v2.y); h1.y = packh2(v2.z, v2.w);
            h1.z = packh2(v3.x, v3.y); h1.w = packh2(v3.z, v3.w);
            const int base = g2 * 16;
            *(uint4*)&Bh[px_l*64 + ((base + 0) ^ ((px_l & 7) << 3))] = h0;
            *(uint4*)&Bh[px_l*64 + ((base + 8) ^ ((px_l & 7) << 3))] = h1;
        }
        __syncthreads();
        #pragma unroll
        for (int kss = 0; kss < 2; ++kss) {
            const int kk0 = kss*32 + lq*8;
            f16x8 a0, a1, bfr;
            {
                const int m0 = l16, m1 = 16 + l16;
                a0 = lds_ldh8(&A0[m0*64 + (kk0 ^ ((m0 & 7) << 3))]);
                a1 = lds_ldh8(&A0[m1*64 + (kk0 ^ ((m1 & 7) << 3))]);
            }
            {
                const int n = wv*16 + l16;
                bfr = lds_ldh8(&Bh[n*64 + (kk0 ^ ((n & 7) << 3))]);
            }
            acc[0] = __builtin_amdgcn_mfma_f32_16x16x32_f16(a0, bfr, acc[0], 0, 0, 0);
            acc[1] = __builtin_amdgcn_mfma_f32_16x16x32_f16(a1, bfr, acc[1], 0, 0, 0);
        }
    }
    const int n = bn0 + wv*16 + l16;
    const int hw2 = n - x8*HW;
    #pragma unroll
    for (int mf = 0; mf < 2; ++mf) {
        #pragma unroll
        for (int r = 0; r < 4; ++r) {
            const int m = mf*16 + lq*4 + r;
            if (m < 18)
                atomicAdd(&off[((size_t)x8*18 + m)*HW + hw2], acc[mf][r]);
        }
    }
}

// ---------------------------------------------------------------------------
// K2b: compact bilinear meta per (tap, pixel): int4 {y0|x0<<16, ly, lx, 0}.
// ---------------------------------------------------------------------------
__global__ void k2b_meta(const float* __restrict__ off, const float* __restrict__ b_off,
                         int* __restrict__ meta)
{
    int id = blockIdx.x*256 + threadIdx.x;
    if (id >= KTAP*NPIX) return;
    int k = id / NPIX, np = id % NPIX;
    int b = np / HW, hw = np % HW;
    int h = hw / WW, w = hw % WW;
    float dy = off[((size_t)b*18 + 2*k    )*HW + hw] + b_off[2*k];
    float dx = off[((size_t)b*18 + 2*k + 1)*HW + hw] + b_off[2*k + 1];
    float py = (float)(h - 1 + (k / 3)) + dy;
    float px = (float)(w - 1 + (k % 3)) + dx;
    py = fminf(fmaxf(py, -30000.f), 30000.f);
    px = fminf(fmaxf(px, -30000.f), 30000.f);
    float y0f = floorf(py), x0f = floorf(px);
    int y0 = (int)y0f, x0 = (int)x0f;
    float ly = py - y0f, lx = px - x0f;
    int4 m;
    m.x = (y0 & 0xFFFF) | ((x0 & 0xFFFF) << 16);
    m.y = __float_as_int(ly);
    m.z = __float_as_int(lx);
    m.w = 0;
    *(int4*)&meta[(k*NPIX + np)*4] = m;
}

// ---------------------------------------------------------------------------
// K3: pipelined fused gather + fp16 MFMA (A single / B hi+lo) + BN + ReLU.
// grid 392 = 8 xcd * 49 tiles (image per XCD); 512 thr; BM=256, BN=64, BK=64.
// ---------------------------------------------------------------------------
__global__ __launch_bounds__(512, 4) void k3_main(
    const float* __restrict__ xt, const int* __restrict__ meta,
    const ushortT* __restrict__ Ah_g, const float* __restrict__ scale_g,
    const float* __restrict__ shift_g, float* __restrict__ out)
{
    __shared__ __align__(16) ushortT Ah_t[256*64];     // 32 KB
    __shared__ __align__(16) ushortT Bh_t[2][64*64];   // 2 x 8 KB
    __shared__ __align__(16) ushortT Bl_t[2][64*64];   // 2 x 8 KB
    __shared__ float s_scale[256], s_shift[256];

    const int tid = threadIdx.x;
    const int bimg = blockIdx.x & 7;                  // xcd == image
    const int lt   = blockIdx.x >> 3;                 // [0,49)
    const int tile = bimg*49 + lt;
    const int bn0  = tile * 64;
    if (tid < 256) { s_scale[tid] = scale_g[tid]; s_shift[tid] = shift_g[tid]; }

    const int wv = tid >> 6, lane = tid & 63;
    const int l16 = lane & 15, lq = lane >> 4;
    const int mbase = (wv >> 1) * 64;
    const int nbase = (wv & 1) * 32;
    const int px_l = tid >> 3, g = tid & 7;
    const int np = bn0 + px_l;

    int   mi[4];
    float mwv[4];
    f32x4 Gc[4][2];
    f32x4 acc[4][2] = {};

    #define LOAD_META(tap_) do {                                               \
        int4 m_ = *(const int4*)&meta[((tap_)*NPIX + np)*4];                   \
        int y0_ = (short)(m_.x & 0xFFFF);                                      \
        int x0_ = (short)(((unsigned)m_.x) >> 16);                             \
        float ly_ = __int_as_float(m_.y), lx_ = __int_as_float(m_.z);          \
        float wy0_ = 1.f - ly_, wx0_ = 1.f - lx_;                              \
        _Pragma("unroll")                                                      \
        for (int c_ = 0; c_ < 4; ++c_) {                                       \
            int yi_ = y0_ + (c_ >> 1), xi_ = x0_ + (c_ & 1);                   \
            bool v_ = (yi_ >= 0) && (yi_ < HH) && (xi_ >= 0) && (xi_ < WW);    \
            int yc_ = min(max(yi_, 0), HH-1), xc_ = min(max(xi_, 0), WW-1);    \
            mi[c_] = (bimg*HW + yc_*WW + xc_)*CIN;                             \
            float wy_ = (c_ >> 1) ? ly_ : wy0_;                                \
            float wx_ = (c_ & 1) ? lx_ : wx0_;                                 \
            mwv[c_] = v_ ? wy_*wx_ : 0.f;                                      \
        }                                                                      \
    } while (0)

    #define ISSUE_GATHER(j_) do {                                              \
        const float* base_ = xt + ((j_) & 3)*64 + g*8;                         \
        _Pragma("unroll")                                                      \
        for (int c_ = 0; c_ < 4; ++c_) {                                       \
            const float* p_ = base_ + mi[c_];                                  \
            Gc[c_][0] = *(const f32x4*)p_;                                     \
            Gc[c_][1] = *(const f32x4*)(p_ + 4);                               \
        }                                                                      \
    } while (0)

    #define BLEND_WRITE(nxt_) do {                                             \
        float v_[8];                                                           \
        _Pragma("unroll")                                                      \
        for (int q_ = 0; q_ < 4; ++q_) {                                       \
            v_[q_]   = mwv[0]*Gc[0][0][q_] + mwv[1]*Gc[1][0][q_]               \
                     + mwv[2]*Gc[2][0][q_] + mwv[3]*Gc[3][0][q_];              \
            v_[4+q_] = mwv[0]*Gc[0][1][q_] + mwv[1]*Gc[1][1][q_]               \
                     + mwv[2]*Gc[2][1][q_] + mwv[3]*Gc[3][1][q_];              \
        }                                                                      \
        uint4 hi_, lo_;                                                        \
        float r_[8];                                                           \
        _Pragma("unroll")                                                      \
        for (int q_ = 0; q_ < 8; ++q_) {                                       \
            _Float16 hh_ = (_Float16)v_[q_];                                   \
            r_[q_] = v_[q_] - (float)hh_;                                      \
        }                                                                      \
        hi_.x = packh2(v_[0], v_[1]); hi_.y = packh2(v_[2], v_[3]);            \
        hi_.z = packh2(v_[4], v_[5]); hi_.w = packh2(v_[6], v_[7]);            \
        lo_.x = packh2(r_[0], r_[1]); lo_.y = packh2(r_[2], r_[3]);            \
        lo_.z = packh2(r_[4], r_[5]); lo_.w = packh2(r_[6], r_[7]);            \
        const int idx_ = px_l*64 + ((g*8) ^ ((px_l & 7) << 3));                \
        *(uint4*)&Bh_t[nxt_][idx_] = hi_;                                      \
        *(uint4*)&Bl_t[nxt_][idx_] = lo_;                                      \
    } while (0)

    #define ISSUE_A(j_) do {                                                   \
        const char* gs_ = (const char*)Ah_g + (size_t)(j_)*32768;              \
        _Pragma("unroll")                                                      \
        for (int it_ = 0; it_ < 4; ++it_)                                      \
            __builtin_amdgcn_global_load_lds(                                  \
                (const __attribute__((address_space(1))) unsigned*)(gs_ + it_*8192 + tid*16), \
                (__attribute__((address_space(3))) unsigned*)((char*)Ah_t + it_*8192 + wv*1024), \
                16, 0, 0);                                                     \
    } while (0)

    #define MFMA_PHASE(cur_) do {                                              \
        __builtin_amdgcn_s_setprio(1);                                         \
        _Pragma("unroll")                                                      \
        for (int ks_ = 0; ks_ < 2; ++ks_) {                                    \
            const int kk0_ = ks_*32 + lq*8;                                    \
            f16x8 a_[4], bh_[2], bl_[2];                                       \
            _Pragma("unroll")                                                  \
            for (int mf_ = 0; mf_ < 4; ++mf_) {                                \
                const int m_ = mbase + mf_*16 + l16;                           \
                a_[mf_] = lds_ldh8(&Ah_t[m_*64 + (kk0_ ^ ((m_ & 7) << 3))]);   \
            }                                                                  \
            _Pragma("unroll")                                                  \
            for (int nf_ = 0; nf_ < 2; ++nf_) {                                \
                const int n_ = nbase + nf_*16 + l16;                           \
                const int ix_ = n_*64 + (kk0_ ^ ((n_ & 7) << 3));              \
                bh_[nf_] = lds_ldh8(&Bh_t[cur_][ix_]);                         \
                bl_[nf_] = lds_ldh8(&Bl_t[cur_][ix_]);                         \
            }                                                                  \
            _Pragma("unroll")                                                  \
            for (int mf_ = 0; mf_ < 4; ++mf_) {                                \
                _Pragma("unroll")                                              \
                for (int nf_ = 0; nf_ < 2; ++nf_) {                            \
                    acc[mf_][nf_] = __builtin_amdgcn_mfma_f32_16x16x32_f16(a_[mf_], bh_[nf_], acc[mf_][nf_], 0, 0, 0); \
                    acc[mf_][nf_] = __builtin_amdgcn_mfma_f32_16x16x32_f16(a_[mf_], bl_[nf_], acc[mf_][nf_], 0, 0, 0); \
                }                                                              \
            }                                                                  \
        }                                                                      \
        __builtin_amdgcn_s_setprio(0);                                         \
    } while (0)

    // ---- prologue: tile 0 ----
    LOAD_META(0);
    ISSUE_GATHER(0);
    ISSUE_A(0);                          // A(0) in flight
    BLEND_WRITE(0);                      // compiler waits exactly the G loads
    asm volatile("s_waitcnt lgkmcnt(0)" ::: "memory");
    __builtin_amdgcn_s_barrier();        // B[0] visible; A(0) still flying

    for (int kt = 0; kt < NKT; ++kt) {
        const int cur = kt & 1;
        if (kt + 1 < NKT) {
            if (((kt + 1) & 3) == 0) LOAD_META((kt + 1) >> 2);
            ISSUE_GATHER(kt + 1);        // 8 dwordx4, newest in stream
            // retire everything except the 8 newest -> my A(kt) loads done
            asm volatile("s_waitcnt vmcnt(8)" ::: "memory");
        } else {
            asm volatile("s_waitcnt vmcnt(0)" ::: "memory");
        }
        __builtin_amdgcn_s_barrier();    // ALL waves' A(kt) landed; B[cur] ready
        __builtin_amdgcn_sched_barrier(0);
        MFMA_PHASE(cur);
        if (kt + 1 < NKT) BLEND_WRITE(cur ^ 1);
        asm volatile("s_waitcnt lgkmcnt(0)" ::: "memory");
        __builtin_amdgcn_s_barrier();    // MFMA(kt) done (A free); B[nxt] visible
        if (kt + 1 < NKT) ISSUE_A(kt + 1);
    }

    // ---- epilogue: BN + ReLU + store ----
    const int hwb = lt * 64;
    #pragma unroll
    for (int mf = 0; mf < 4; ++mf) {
        #pragma unroll
        for (int nf = 0; nf < 2; ++nf) {
            const int hwloc = hwb + nbase + nf*16 + l16;
            const int m0 = mbase + mf*16 + lq*4;
            float* op = out + ((size_t)bimg*COUT + m0)*HW + hwloc;
            const f32x4 v = acc[mf][nf];
            #pragma unroll
            for (int r = 0; r < 4; ++r) {
                float val = fmaxf(v[r]*s_scale[m0 + r] + s_shift[m0 + r], 0.f);
                op[(size_t)r*HW] = val;
            }
        }
    }
    #undef LOAD_META
    #undef ISSUE_GATHER
    #undef BLEND_WRITE
    #undef ISSUE_A
    #undef MFMA_PHASE
}

// ---------------------------------------------------------------------------
extern "C" void kernel_launch(void* const* d_in, const int* in_sizes, int n_in,
                              void* d_out, int out_size, void* d_ws, size_t ws_size,
                              hipStream_t stream)
{
    const float* x      = (const float*)d_in[0];
    const float* w_off  = (const float*)d_in[1];
    const float* b_off  = (const float*)d_in[2];
    const float* w_conv = (const float*)d_in[3];
    const float* gamma  = (const float*)d_in[4];
    const float* beta   = (const float*)d_in[5];
    const float* rmean  = (const float*)d_in[6];
    const float* rvar   = (const float*)d_in[7];
    float* out = (float*)d_out;
    char* ws = (char*)d_ws;

    // workspace layout (bytes), total ~32.5 MB
    float*   xt    = (float*)(ws + 0);           // 25690112 B
    float*   off   = (float*)(ws + 25690112);    //  1806336 B (atomic-summed)
    int*     meta  = (int*)  (ws + 27496448);    //  3612672 B (int4 per tap-px)
    ushortT* Ah    = (ushortT*)(ws + 31109120);  //  1179648 B
    ushortT* A0h   = (ushortT*)(ws + 32288768);  //   147456 B
    float*   scale = (float*)(ws + 32436224);    //     1024 B
    float*   shift = (float*)(ws + 32437248);    //     1024 B

    hipMemsetAsync(off, 0, 1806336, stream);     // k1 accumulates atomically
    hipLaunchKernelGGL(k0_transpose, dim3(1568), dim3(256), 0, stream, x, xt);
    hipLaunchKernelGGL(k2a_prep, dim3((COUT*KG + 32*KG + 256 + 255)/256), dim3(256), 0, stream,
                       w_conv, w_off, gamma, beta, rmean, rvar, Ah, A0h, scale, shift);
    hipLaunchKernelGGL(k1_offmfma, dim3(1568), dim3(256), 0, stream, xt, A0h, off);
    hipLaunchKernelGGL(k2b_meta, dim3((KTAP*NPIX + 255)/256), dim3(256), 0, stream,
                       off, b_off, meta);
    hipLaunchKernelGGL(k3_main, dim3(392), dim3(512), 0, stream,
                       xt, meta, Ah, scale, shift, out);
}